// Round 2
// baseline (345.449 us; speedup 1.0000x reference)
//
#include <hip/hip_runtime.h>
#include <hip/hip_bf16.h>

typedef __attribute__((ext_vector_type(8))) short bf16x8;   // 8 bf16 in 4 VGPRs
typedef __attribute__((ext_vector_type(4))) float f32x4;
typedef unsigned short u16;
typedef unsigned int u32;

#define DEV __device__ __forceinline__

DEV float bf2f(u16 v) { u32 u = ((u32)v) << 16; return __builtin_bit_cast(float, u); }
DEV u16 f2bf(float f) {
    u32 u = __builtin_bit_cast(u32, f);
    u32 r = (u + 0x7FFFu + ((u >> 16) & 1u)) >> 16;
    return (u16)r;
}

DEV void gll16(const u16* g, u16* l) {
    // 16B per lane; LDS dest = wave-uniform base + lane*16 (linear), global src per-lane
    __builtin_amdgcn_global_load_lds((const __attribute__((address_space(1))) void*)g,
                                     (__attribute__((address_space(3))) void*)l, 16, 0, 0);
}

// ---------------------------------------------------------------------------
// Dtype detect: bits[14:7] of u32 words = 2nd packed-bf16 exponent (clustered)
// if bf16, uniform mantissa bits if fp32.
// ---------------------------------------------------------------------------
__global__ void detect_kernel(const u32* __restrict__ x, int* __restrict__ flag) {
    __shared__ int cnt;
    if (threadIdx.x == 0) cnt = 0;
    __syncthreads();
    int c = 0;
    for (int i = threadIdx.x; i < 4096; i += 256) {
        u32 w = x[i];
        u32 e = (w >> 7) & 0xFF;
        c += (e >= 110 && e <= 132) ? 1 : 0;
    }
    atomicAdd(&cnt, c);
    __syncthreads();
    if (threadIdx.x == 0) *flag = (cnt * 2 > 4096) ? 1 : 0;   // 1 = bf16, 0 = fp32
}

// normalize any input tensor to bf16 (n8 = elems/8)
__global__ void cvt_bf16_kernel(const void* __restrict__ in, u16* __restrict__ out,
                                int n8, const int* __restrict__ flag) {
    const int fl = *flag;
    int i = blockIdx.x * 256 + threadIdx.x;
    const int stride = gridDim.x * 256;
    if (fl) {
        const bf16x8* ip = (const bf16x8*)in;
        bf16x8* op = (bf16x8*)out;
        for (; i < n8; i += stride) op[i] = ip[i];
    } else {
        const float4* ip = (const float4*)in;
        bf16x8* op = (bf16x8*)out;
        for (; i < n8; i += stride) {
            float4 a = ip[2 * i], b = ip[2 * i + 1];
            bf16x8 o;
            o[0] = (short)f2bf(a.x); o[1] = (short)f2bf(a.y);
            o[2] = (short)f2bf(a.z); o[3] = (short)f2bf(a.w);
            o[4] = (short)f2bf(b.x); o[5] = (short)f2bf(b.y);
            o[6] = (short)f2bf(b.z); o[7] = (short)f2bf(b.w);
            op[i] = o;
        }
    }
}

// normalize bias to fp32
__global__ void cvt_f32_kernel(const void* __restrict__ in, float* __restrict__ out,
                               int n, const int* __restrict__ flag) {
    const int fl = *flag;
    int i = blockIdx.x * 256 + threadIdx.x;
    if (i < n) out[i] = fl ? bf2f(((const u16*)in)[i]) : ((const float*)in)[i];
}

// ---------------------------------------------------------------------------
// RoPE cos/sin table: [768][512] float2
// ---------------------------------------------------------------------------
__global__ void rope_table_kernel(float2* __restrict__ tab) {
    int idx = blockIdx.x * 256 + threadIdx.x;   // 768*512 threads
    int t = idx >> 9, j = idx & 511;
    float freq = expf(-(float)(2 * j) * (9.210340371976184f / 1024.0f)); // 10000^(-2j/1024)
    float ang = (float)t * freq;
    tab[idx] = make_float2(cosf(ang), sinf(ang));
}

// ---------------------------------------------------------------------------
// In-place RoPE on q and k halves of qkv [12288][3072]
// ---------------------------------------------------------------------------
__global__ void rope_apply_kernel(u16* __restrict__ qkv, const float2* __restrict__ tab) {
    int idx = blockIdx.x * 256 + threadIdx.x;   // 12288*128 threads
    int bt = idx >> 7, j4 = idx & 127;
    int t = bt % 768;
    size_t base = (size_t)bt * 3072 + j4 * 8;
    bf16x8 q = *(const bf16x8*)(qkv + base);
    bf16x8 k = *(const bf16x8*)(qkv + base + 1024);
    const float2* tp = tab + t * 512 + j4 * 4;
    bf16x8 qo, ko;
#pragma unroll
    for (int e = 0; e < 4; ++e) {
        float2 cs = tp[e];
        float qr = bf2f((u16)q[2 * e]), qi = bf2f((u16)q[2 * e + 1]);
        qo[2 * e]     = (short)f2bf(qr * cs.x - qi * cs.y);
        qo[2 * e + 1] = (short)f2bf(qr * cs.y + qi * cs.x);
        float kr = bf2f((u16)k[2 * e]), ki = bf2f((u16)k[2 * e + 1]);
        ko[2 * e]     = (short)f2bf(kr * cs.x - ki * cs.y);
        ko[2 * e + 1] = (short)f2bf(kr * cs.y + ki * cs.x);
    }
    *(bf16x8*)(qkv + base) = qo;
    *(bf16x8*)(qkv + base + 1024) = ko;
}

// ---------------------------------------------------------------------------
// GEMM: C[M][N] = A[M][K] @ W[N][K]^T + bias (m97 structure)
// out_mode==1: store fp32 when *flag==0, else bf16
// ---------------------------------------------------------------------------
__global__ __launch_bounds__(256)
void gemm_bias_kernel(const u16* __restrict__ A, const u16* __restrict__ W,
                      const float* __restrict__ bias, void* __restrict__ C,
                      int M, int N, int K, const int* __restrict__ flag, int out_mode) {
    __shared__ u16 As[128 * 32];
    __shared__ u16 Bs[128 * 32];
    const int tid = threadIdx.x;
    const int l = tid & 63, w = tid >> 6;
    const int M0 = blockIdx.x * 128, N0 = blockIdx.y * 128;
    const int wr = (w >> 1) * 64, wc = (w & 1) * 64;
    const int lo = l & 15, hi = l >> 4;
    const int kk = hi * 8;
    const int f32out = out_mode ? (*flag == 0) : 0;

    const int srow = w * 32 + (l >> 2);
    const int scol = (l & 3) * 8;
    const u16* Ag = A + (size_t)(M0 + srow) * K + scol;
    const u16* Wg = W + (size_t)(N0 + srow) * K + scol;
    const size_t rowK16 = (size_t)16 * K;
    u16* AsW = As + w * 1024;
    u16* BsW = Bs + w * 1024;

    f32x4 acc[4][4] = {};

    for (int k0 = 0; k0 < K; k0 += 32) {
        __syncthreads();
        gll16(Ag + k0, AsW);
        gll16(Ag + k0 + rowK16, AsW + 512);
        gll16(Wg + k0, BsW);
        gll16(Wg + k0 + rowK16, BsW + 512);
        __syncthreads();

        bf16x8 a[4], b[4];
#pragma unroll
        for (int m = 0; m < 4; ++m)
            a[m] = *(const bf16x8*)&As[(wr + m * 16 + lo) * 32 + kk];
#pragma unroll
        for (int n = 0; n < 4; ++n)
            b[n] = *(const bf16x8*)&Bs[(wc + n * 16 + lo) * 32 + kk];
#pragma unroll
        for (int m = 0; m < 4; ++m)
#pragma unroll
            for (int n = 0; n < 4; ++n)
                acc[m][n] = __builtin_amdgcn_mfma_f32_16x16x32_bf16(a[m], b[n], acc[m][n], 0, 0, 0);
    }

    // C/D layout: col=lane&15, row=(lane>>4)*4+j  [m89-verified]
    const int col0 = N0 + wc + lo;
    const int row0 = M0 + wr + hi * 4;
#pragma unroll
    for (int n = 0; n < 4; ++n) {
        float bi = bias[col0 + n * 16];
#pragma unroll
        for (int m = 0; m < 4; ++m)
#pragma unroll
            for (int j = 0; j < 4; ++j) {
                float v = acc[m][n][j] + bi;
                size_t idx = (size_t)(row0 + m * 16 + j) * N + col0 + n * 16;
                if (f32out) ((float*)C)[idx] = v;
                else        ((u16*)C)[idx] = f2bf(v);
            }
    }
}

// ---------------------------------------------------------------------------
// Flash attention: block = (qt, h, b), 64 q-rows, 4 waves x 16 rows
// ---------------------------------------------------------------------------
__global__ __launch_bounds__(256)
void attn_kernel(const u16* __restrict__ qkv, u16* __restrict__ y) {
    constexpr int T = 768, CH = 1024, QKVC = 3072;
    constexpr float NEG = -30000.0f;
    __shared__ u16 Ks[64 * 64];    // K tile [key][d], linear for global_load_lds
    __shared__ u16 Vt[64 * 72];    // V^T tile [d][key], padded stride 72
    __shared__ u16 Ps[64 * 72];    // P tile [q][key], padded stride 72

    const int tid = threadIdx.x, l = tid & 63, w = tid >> 6;
    const int qt = blockIdx.x, h = blockIdx.y, b = blockIdx.z;
    const int lo = l & 15, hi = l >> 4;
    const int kk = hi * 8;

    const int qrow = qt * 64 + w * 16 + lo;
    const u16* qptr = qkv + (size_t)(b * T + qrow) * QKVC + h * 64 + kk;
    bf16x8 aq0 = *(const bf16x8*)qptr;
    bf16x8 aq1 = *(const bf16x8*)(qptr + 32);

    f32x4 o[4] = {};
    float mrun[4] = {NEG, NEG, NEG, NEG};
    float lrun[4] = {0.f, 0.f, 0.f, 0.f};

    const int ksr = w * 16 + (l >> 3);
    const int ksc = (l & 7) * 8;
    const u16* kbase = qkv + (size_t)(b * T + ksr) * QKVC + CH + h * 64 + ksc;

    for (int kt = 0; kt <= qt; ++kt) {
        __syncthreads();                       // prev iter LDS reads done
        const size_t ktoff = (size_t)(kt * 64) * QKVC;
        gll16(kbase + ktoff, Ks + w * 1024);
        gll16(kbase + ktoff + (size_t)8 * QKVC, Ks + w * 1024 + 512);
#pragma unroll
        for (int c2 = 0; c2 < 2; ++c2) {
            int slot = c2 * 256 + tid;
            int vrow = slot >> 3, vd0 = (slot & 7) * 8;
            bf16x8 vv = *(const bf16x8*)(qkv + (size_t)(b * T + kt * 64 + vrow) * QKVC + 2 * CH + h * 64 + vd0);
#pragma unroll
            for (int e = 0; e < 8; ++e)
                Vt[(vd0 + e) * 72 + vrow] = (u16)vv[e];
        }
        __syncthreads();                       // drains gll (vmcnt0) + Vt writes

        f32x4 s[4];
#pragma unroll
        for (int n = 0; n < 4; ++n) {
            bf16x8 kb0 = *(const bf16x8*)&Ks[(n * 16 + lo) * 64 + kk];
            bf16x8 kb1 = *(const bf16x8*)&Ks[(n * 16 + lo) * 64 + 32 + kk];
            f32x4 z = {0.f, 0.f, 0.f, 0.f};
            z = __builtin_amdgcn_mfma_f32_16x16x32_bf16(aq0, kb0, z, 0, 0, 0);
            z = __builtin_amdgcn_mfma_f32_16x16x32_bf16(aq1, kb1, z, 0, 0, 0);
            s[n] = z * 0.125f;
        }
        if (kt == qt) {   // causal mask inside diagonal tile
#pragma unroll
            for (int n = 0; n < 4; ++n) {
                int kcol = n * 16 + lo;
#pragma unroll
                for (int j = 0; j < 4; ++j)
                    if (kcol > w * 16 + hi * 4 + j) s[n][j] = NEG;
            }
        }
        float mnew[4], corr[4];
#pragma unroll
        for (int j = 0; j < 4; ++j) {
            float mx = fmaxf(fmaxf(s[0][j], s[1][j]), fmaxf(s[2][j], s[3][j]));
            mx = fmaxf(mx, __shfl_xor(mx, 1));
            mx = fmaxf(mx, __shfl_xor(mx, 2));
            mx = fmaxf(mx, __shfl_xor(mx, 4));
            mx = fmaxf(mx, __shfl_xor(mx, 8));
            mnew[j] = fmaxf(mrun[j], mx);
            corr[j] = __expf(mrun[j] - mnew[j]);
            mrun[j] = mnew[j];
        }
        float p[4][4];
#pragma unroll
        for (int n = 0; n < 4; ++n)
#pragma unroll
            for (int j = 0; j < 4; ++j)
                p[n][j] = __expf(s[n][j] - mnew[j]);
#pragma unroll
        for (int j = 0; j < 4; ++j) {
            float r = p[0][j] + p[1][j] + p[2][j] + p[3][j];
            r += __shfl_xor(r, 1);
            r += __shfl_xor(r, 2);
            r += __shfl_xor(r, 4);
            r += __shfl_xor(r, 8);
            lrun[j] = lrun[j] * corr[j] + r;
        }
#pragma unroll
        for (int n = 0; n < 4; ++n)
#pragma unroll
            for (int j = 0; j < 4; ++j)
                o[n][j] *= corr[j];
#pragma unroll
        for (int n = 0; n < 4; ++n)
#pragma unroll
            for (int j = 0; j < 4; ++j)
                Ps[(w * 16 + hi * 4 + j) * 72 + n * 16 + lo] = f2bf(p[n][j]);

#pragma unroll
        for (int c = 0; c < 2; ++c) {
            bf16x8 pa = *(const bf16x8*)&Ps[(w * 16 + lo) * 72 + c * 32 + kk];
#pragma unroll
            for (int n = 0; n < 4; ++n) {
                bf16x8 vb = *(const bf16x8*)&Vt[(n * 16 + lo) * 72 + c * 32 + kk];
                o[n] = __builtin_amdgcn_mfma_f32_16x16x32_bf16(pa, vb, o[n], 0, 0, 0);
            }
        }
    }

    float inv[4];
#pragma unroll
    for (int j = 0; j < 4; ++j) inv[j] = (lrun[j] > 0.f) ? 1.0f / lrun[j] : 0.f;
#pragma unroll
    for (int n = 0; n < 4; ++n)
#pragma unroll
        for (int j = 0; j < 4; ++j) {
            int t = qt * 64 + w * 16 + hi * 4 + j;
            y[(size_t)(b * T + t) * CH + h * 64 + n * 16 + lo] = f2bf(o[n][j] * inv[j]);
        }
}

// ---------------------------------------------------------------------------
extern "C" void kernel_launch(void* const* d_in, const int* in_sizes, int n_in,
                              void* d_out, int out_size, void* d_ws, size_t ws_size,
                              hipStream_t stream) {
    char* ws = (char*)d_ws;
    int*   flag  = (int*)ws;                                 // @0, reserve 256B
    u16*   xb    = (u16*)(ws + 256);                         // 25165824 B
    u16*   Wqb   = (u16*)(ws + 256 + 25165824);              // 6291456 B
    u16*   Wob   = (u16*)(ws + 256 + 31457280);              // 2097152 B
    float* bqf   = (float*)(ws + 256 + 33554432);            // 12288 B
    float* bof   = (float*)(ws + 256 + 33566720);            // 4096 B
    u16*   qkv   = (u16*)(ws + 256 + 33570816);              // 75497472 B
    u16*   y     = (u16*)(ws + 256 + 109068288);             // 25165824 B
    float2* tab  = (float2*)(ws + 256 + 134234112);          // 3145728 B  (total ~131 MB)

    detect_kernel<<<1, 256, 0, stream>>>((const u32*)d_in[0], flag);
    cvt_bf16_kernel<<<2048, 256, 0, stream>>>(d_in[0], xb,  12582912 / 8, flag);
    cvt_bf16_kernel<<<1536, 256, 0, stream>>>(d_in[1], Wqb, 3145728 / 8, flag);
    cvt_bf16_kernel<<<512,  256, 0, stream>>>(d_in[3], Wob, 1048576 / 8, flag);
    cvt_f32_kernel<<<12, 256, 0, stream>>>(d_in[2], bqf, 3072, flag);
    cvt_f32_kernel<<<4,  256, 0, stream>>>(d_in[4], bof, 1024, flag);

    rope_table_kernel<<<768 * 512 / 256, 256, 0, stream>>>(tab);
    gemm_bias_kernel<<<dim3(96, 24), 256, 0, stream>>>(xb, Wqb, bqf, qkv, 12288, 3072, 1024, flag, 0);
    rope_apply_kernel<<<12288 * 128 / 256, 256, 0, stream>>>(qkv, tab);
    attn_kernel<<<dim3(12, 16, 16), 256, 0, stream>>>(qkv, y);
    gemm_bias_kernel<<<dim3(96, 8), 256, 0, stream>>>(y, Wob, bof, d_out, 12288, 1024, 1024, flag, 1);
}

// Round 3
// 317.844 us; speedup vs baseline: 1.0868x; 1.0868x over previous
//
#include <hip/hip_runtime.h>
#include <hip/hip_bf16.h>

typedef __attribute__((ext_vector_type(8))) short bf16x8;   // 8 bf16 in 4 VGPRs
typedef __attribute__((ext_vector_type(4))) float f32x4;
typedef unsigned short u16;
typedef unsigned int u32;

#define DEV __device__ __forceinline__

DEV float bf2f(u16 v) { u32 u = ((u32)v) << 16; return __builtin_bit_cast(float, u); }
DEV u16 f2bf(float f) {
    u32 u = __builtin_bit_cast(u32, f);
    u32 r = (u + 0x7FFFu + ((u >> 16) & 1u)) >> 16;
    return (u16)r;
}

DEV void gll16(const u16* g, u16* l) {
    __builtin_amdgcn_global_load_lds((const __attribute__((address_space(1))) void*)g,
                                     (__attribute__((address_space(3))) void*)l, 16, 0, 0);
}

#define WAIT_VM0()   asm volatile("s_waitcnt vmcnt(0)" ::: "memory")
#define WAIT_LGKM0() asm volatile("s_waitcnt lgkmcnt(0)" ::: "memory")
#define BAR()        __builtin_amdgcn_s_barrier()

// ---------------------------------------------------------------------------
// Dtype detect: bits[14:7] of u32 words clustered (bf16 exponent) vs uniform (fp32 mantissa)
// ---------------------------------------------------------------------------
__global__ void detect_kernel(const u32* __restrict__ x, int* __restrict__ flag) {
    __shared__ int cnt;
    if (threadIdx.x == 0) cnt = 0;
    __syncthreads();
    int c = 0;
    for (int i = threadIdx.x; i < 4096; i += 256) {
        u32 w = x[i];
        u32 e = (w >> 7) & 0xFF;
        c += (e >= 110 && e <= 132) ? 1 : 0;
    }
    atomicAdd(&cnt, c);
    __syncthreads();
    if (threadIdx.x == 0) *flag = (cnt * 2 > 4096) ? 1 : 0;   // 1 = bf16, 0 = fp32
}

__global__ void cvt_bf16_kernel(const void* __restrict__ in, u16* __restrict__ out,
                                int n8, const int* __restrict__ flag) {
    const int fl = *flag;
    int i = blockIdx.x * 256 + threadIdx.x;
    const int stride = gridDim.x * 256;
    if (fl) {
        const bf16x8* ip = (const bf16x8*)in;
        bf16x8* op = (bf16x8*)out;
        for (; i < n8; i += stride) op[i] = ip[i];
    } else {
        const float4* ip = (const float4*)in;
        bf16x8* op = (bf16x8*)out;
        for (; i < n8; i += stride) {
            float4 a = ip[2 * i], b = ip[2 * i + 1];
            bf16x8 o;
            o[0] = (short)f2bf(a.x); o[1] = (short)f2bf(a.y);
            o[2] = (short)f2bf(a.z); o[3] = (short)f2bf(a.w);
            o[4] = (short)f2bf(b.x); o[5] = (short)f2bf(b.y);
            o[6] = (short)f2bf(b.z); o[7] = (short)f2bf(b.w);
            op[i] = o;
        }
    }
}

__global__ void cvt_f32_kernel(const void* __restrict__ in, float* __restrict__ out,
                               int n, const int* __restrict__ flag) {
    const int fl = *flag;
    int i = blockIdx.x * 256 + threadIdx.x;
    if (i < n) out[i] = fl ? bf2f(((const u16*)in)[i]) : ((const float*)in)[i];
}

// ---------------------------------------------------------------------------
// RoPE cos/sin table: [768][512] float2
// ---------------------------------------------------------------------------
__global__ void rope_table_kernel(float2* __restrict__ tab) {
    int idx = blockIdx.x * 256 + threadIdx.x;
    int t = idx >> 9, j = idx & 511;
    float freq = expf(-(float)(2 * j) * (9.210340371976184f / 1024.0f)); // 10000^(-2j/1024)
    float ang = (float)t * freq;
    tab[idx] = make_float2(cosf(ang), sinf(ang));
}

// ---------------------------------------------------------------------------
// GEMM: C[M][N] = A[M][K] @ W[N][K]^T + bias (m97 structure)
// rope!=0: apply RoPE in epilogue to cols < 2048 (q,k regions of qkv output)
// out_mode==1: store fp32 when *flag==0, else bf16
// ---------------------------------------------------------------------------
__global__ __launch_bounds__(256)
void gemm_bias_kernel(const u16* __restrict__ A, const u16* __restrict__ W,
                      const float* __restrict__ bias, void* __restrict__ C,
                      int M, int N, int K, const int* __restrict__ flag, int out_mode,
                      const float2* __restrict__ tab, int rope) {
    __shared__ u16 As[128 * 32];
    __shared__ u16 Bs[128 * 32];
    const int tid = threadIdx.x;
    const int l = tid & 63, w = tid >> 6;
    const int M0 = blockIdx.x * 128, N0 = blockIdx.y * 128;
    const int wr = (w >> 1) * 64, wc = (w & 1) * 64;
    const int lo = l & 15, hi = l >> 4;
    const int kk = hi * 8;
    const int f32out = out_mode ? (*flag == 0) : 0;

    const int srow = w * 32 + (l >> 2);
    const int scol = (l & 3) * 8;
    const u16* Ag = A + (size_t)(M0 + srow) * K + scol;
    const u16* Wg = W + (size_t)(N0 + srow) * K + scol;
    const size_t rowK16 = (size_t)16 * K;
    u16* AsW = As + w * 1024;
    u16* BsW = Bs + w * 1024;

    f32x4 acc[4][4] = {};

    for (int k0 = 0; k0 < K; k0 += 32) {
        __syncthreads();
        gll16(Ag + k0, AsW);
        gll16(Ag + k0 + rowK16, AsW + 512);
        gll16(Wg + k0, BsW);
        gll16(Wg + k0 + rowK16, BsW + 512);
        __syncthreads();

        bf16x8 a[4], b[4];
#pragma unroll
        for (int m = 0; m < 4; ++m)
            a[m] = *(const bf16x8*)&As[(wr + m * 16 + lo) * 32 + kk];
#pragma unroll
        for (int n = 0; n < 4; ++n)
            b[n] = *(const bf16x8*)&Bs[(wc + n * 16 + lo) * 32 + kk];
#pragma unroll
        for (int m = 0; m < 4; ++m)
#pragma unroll
            for (int n = 0; n < 4; ++n)
                acc[m][n] = __builtin_amdgcn_mfma_f32_16x16x32_bf16(a[m], b[n], acc[m][n], 0, 0, 0);
    }

    // C/D layout: col=lane&15, row=(lane>>4)*4+j  [m89-verified]
    const int col0 = N0 + wc + lo;
    const int row0 = M0 + wr + hi * 4;
    const int do_rope = rope && (N0 < 2048);
    const int t0 = (M0 % 768) + wr + hi * 4;    // 128-row tiles never cross batch boundary (768 = 6*128)
#pragma unroll
    for (int n = 0; n < 4; ++n) {
        const int col = col0 + n * 16;
        float bi = bias[col];
        const int jf = (col & 1023) >> 1;
        const int odd = col & 1;
#pragma unroll
        for (int m = 0; m < 4; ++m)
#pragma unroll
            for (int j = 0; j < 4; ++j) {
                float v = acc[m][n][j] + bi;
                if (do_rope) {
                    float partner = __shfl_xor(v, 1);       // lane lo^1 = adjacent column
                    float2 cs = tab[(t0 + m * 16 + j) * 512 + jf];
                    v = odd ? (v * cs.x + partner * cs.y) : (v * cs.x - partner * cs.y);
                }
                size_t idx = (size_t)(row0 + m * 16 + j) * N + col;
                if (f32out) ((float*)C)[idx] = v;
                else        ((u16*)C)[idx] = f2bf(v);
            }
    }
}

// ---------------------------------------------------------------------------
// Flash attention, pipelined: block = (qt, h, b), 64 q-rows, 4 waves x 16 rows
// Ks double-buffered (XOR-swizzled), Vt swizzled, next-tile loads overlap compute
// ---------------------------------------------------------------------------
__global__ __launch_bounds__(256)
void attn_kernel(const u16* __restrict__ qkv, u16* __restrict__ y) {
    constexpr int T = 768, CH = 1024, QKVC = 3072;
    constexpr float NEG = -30000.0f;
    __shared__ u16 Ks[2][64 * 64];  // [key][d], cols XOR-swizzled by (key&7)*8
    __shared__ u16 Vt[64 * 72];     // [d][key], key-col XOR-swizzled by ((d>>3)&7)*8
    __shared__ u16 Ps[64 * 72];     // [q][key], stride-72 (conflict-free as-is)

    const int tid = threadIdx.x, l = tid & 63, w = tid >> 6;
    const int qt = blockIdx.x, h = blockIdx.y, b = blockIdx.z;
    const int lo = l & 15, hi = l >> 4;
    const int kk = hi * 8;
    const int swzk = (lo & 7) * 8;      // Ks read XOR

    // Q fragments, pre-scaled by 1/8 (power-of-2: exact in bf16)
    const int qrow = qt * 64 + w * 16 + lo;
    const u16* qptr = qkv + (size_t)(b * T + qrow) * QKVC + h * 64 + kk;
    bf16x8 aq0r = *(const bf16x8*)qptr;
    bf16x8 aq1r = *(const bf16x8*)(qptr + 32);
    bf16x8 aq0, aq1;
#pragma unroll
    for (int e = 0; e < 8; ++e) {
        aq0[e] = (short)f2bf(bf2f((u16)aq0r[e]) * 0.125f);
        aq1[e] = (short)f2bf(bf2f((u16)aq1r[e]) * 0.125f);
    }

    f32x4 o[4] = {};
    float mrun[4] = {NEG, NEG, NEG, NEG};
    float lrun[4] = {0.f, 0.f, 0.f, 0.f};

    // K staging: wave w stages rows w*16+(l>>3) (+8 second call); source col pre-swizzled
    const int ksr = w * 16 + (l >> 3);
    const int ksc = ((l & 7) ^ ((l >> 3) & 7)) * 8;
    const u16* kbase = qkv + (size_t)(b * T + ksr) * QKVC + CH + h * 64 + ksc;

    // V loads (coalesced): thread covers rows tid>>3 and 32+(tid>>3), d-chunk (tid&7)*8
    const int vd0 = (tid & 7) * 8;
    const int vswz = (tid & 7) * 8;     // = (d>>3)*8, uniform over e
    const int vr0 = tid >> 3, vr1 = 32 + (tid >> 3);
    const u16* vbase = qkv + (size_t)(b * T) * QKVC + 2 * CH + h * 64 + vd0;

    // ---- prologue: stage tile 0 ----
    gll16(kbase, &Ks[0][w * 1024]);
    gll16(kbase + (size_t)8 * QKVC, &Ks[0][w * 1024 + 512]);
    bf16x8 cv0 = *(const bf16x8*)(vbase + (size_t)vr0 * QKVC);
    bf16x8 cv1 = *(const bf16x8*)(vbase + (size_t)vr1 * QKVC);
    WAIT_VM0();
#pragma unroll
    for (int e = 0; e < 8; ++e) {
        Vt[(vd0 + e) * 72 + (vr0 ^ vswz)] = (u16)cv0[e];
        Vt[(vd0 + e) * 72 + (vr1 ^ vswz)] = (u16)cv1[e];
    }

    for (int kt = 0; kt <= qt; ++kt) {
        const int cur = kt & 1, nxt = cur ^ 1;
        bf16x8 nv0, nv1;
        if (kt < qt) {      // issue next-tile loads: fly during compute below
            const size_t koff = (size_t)((kt + 1) * 64) * QKVC;
            gll16(kbase + koff, &Ks[nxt][w * 1024]);
            gll16(kbase + koff + (size_t)8 * QKVC, &Ks[nxt][w * 1024 + 512]);
            const u16* vb2 = vbase + (size_t)((kt + 1) * 64) * QKVC;
            nv0 = *(const bf16x8*)(vb2 + (size_t)vr0 * QKVC);
            nv1 = *(const bf16x8*)(vb2 + (size_t)vr1 * QKVC);
        }
        WAIT_LGKM0();       // own Vt/Ps writes done
        BAR();              // all waves: Vt + Ks[cur] ready (each drained own vmcnt last iter)

        __builtin_amdgcn_s_setprio(1);
        // S = (Q/8) K^T
        f32x4 s[4];
#pragma unroll
        for (int n = 0; n < 4; ++n) {
            bf16x8 kb0 = *(const bf16x8*)&Ks[cur][(n * 16 + lo) * 64 + (kk ^ swzk)];
            bf16x8 kb1 = *(const bf16x8*)&Ks[cur][(n * 16 + lo) * 64 + ((32 + kk) ^ swzk)];
            f32x4 z = {0.f, 0.f, 0.f, 0.f};
            z = __builtin_amdgcn_mfma_f32_16x16x32_bf16(aq0, kb0, z, 0, 0, 0);
            z = __builtin_amdgcn_mfma_f32_16x16x32_bf16(aq1, kb1, z, 0, 0, 0);
            s[n] = z;
        }
        __builtin_amdgcn_s_setprio(0);

        if (kt == qt) {     // causal mask on diagonal tile
#pragma unroll
            for (int n = 0; n < 4; ++n) {
                int kcol = n * 16 + lo;
#pragma unroll
                for (int j = 0; j < 4; ++j)
                    if (kcol > w * 16 + hi * 4 + j) s[n][j] = NEG;
            }
        }
        float mnew[4], corr[4];
#pragma unroll
        for (int j = 0; j < 4; ++j) {
            float mx = fmaxf(fmaxf(s[0][j], s[1][j]), fmaxf(s[2][j], s[3][j]));
            mx = fmaxf(mx, __shfl_xor(mx, 1));
            mx = fmaxf(mx, __shfl_xor(mx, 2));
            mx = fmaxf(mx, __shfl_xor(mx, 4));
            mx = fmaxf(mx, __shfl_xor(mx, 8));
            mnew[j] = fmaxf(mrun[j], mx);
            corr[j] = __expf(mrun[j] - mnew[j]);
            mrun[j] = mnew[j];
        }
        float p[4][4];
#pragma unroll
        for (int n = 0; n < 4; ++n)
#pragma unroll
            for (int j = 0; j < 4; ++j)
                p[n][j] = __expf(s[n][j] - mnew[j]);
#pragma unroll
        for (int j = 0; j < 4; ++j) {
            float r = p[0][j] + p[1][j] + p[2][j] + p[3][j];
            r += __shfl_xor(r, 1);
            r += __shfl_xor(r, 2);
            r += __shfl_xor(r, 4);
            r += __shfl_xor(r, 8);
            lrun[j] = lrun[j] * corr[j] + r;
        }
#pragma unroll
        for (int n = 0; n < 4; ++n)
#pragma unroll
            for (int j = 0; j < 4; ++j)
                o[n][j] *= corr[j];
#pragma unroll
        for (int n = 0; n < 4; ++n)
#pragma unroll
            for (int j = 0; j < 4; ++j)
                Ps[(w * 16 + hi * 4 + j) * 72 + n * 16 + lo] = f2bf(p[n][j]);

        __builtin_amdgcn_s_setprio(1);
#pragma unroll
        for (int c = 0; c < 2; ++c) {
            bf16x8 pa = *(const bf16x8*)&Ps[(w * 16 + lo) * 72 + c * 32 + kk];
#pragma unroll
            for (int n = 0; n < 4; ++n) {
                const int v = (n * 2 + (lo >> 3)) & 7;
                bf16x8 vb = *(const bf16x8*)&Vt[(n * 16 + lo) * 72 + ((c * 32 + kk) ^ (v * 8))];
                o[n] = __builtin_amdgcn_mfma_f32_16x16x32_bf16(pa, vb, o[n], 0, 0, 0);
            }
        }
        __builtin_amdgcn_s_setprio(0);

        if (kt < qt) {
            WAIT_VM0();     // next Ks gll + nv regs landed (hidden under compute above)
            BAR();          // all waves done reading Vt; all Ks[nxt] staged
#pragma unroll
            for (int e = 0; e < 8; ++e) {
                Vt[(vd0 + e) * 72 + (vr0 ^ vswz)] = (u16)nv0[e];
                Vt[(vd0 + e) * 72 + (vr1 ^ vswz)] = (u16)nv1[e];
            }
        }
    }

    float inv[4];
#pragma unroll
    for (int j = 0; j < 4; ++j) inv[j] = (lrun[j] > 0.f) ? 1.0f / lrun[j] : 0.f;
#pragma unroll
    for (int n = 0; n < 4; ++n)
#pragma unroll
        for (int j = 0; j < 4; ++j) {
            int t = qt * 64 + w * 16 + hi * 4 + j;
            y[(size_t)(b * T + t) * CH + h * 64 + n * 16 + lo] = f2bf(o[n][j] * inv[j]);
        }
}

// ---------------------------------------------------------------------------
extern "C" void kernel_launch(void* const* d_in, const int* in_sizes, int n_in,
                              void* d_out, int out_size, void* d_ws, size_t ws_size,
                              hipStream_t stream) {
    char* ws = (char*)d_ws;
    int*   flag  = (int*)ws;
    u16*   xb    = (u16*)(ws + 256);
    u16*   Wqb   = (u16*)(ws + 256 + 25165824);
    u16*   Wob   = (u16*)(ws + 256 + 31457280);
    float* bqf   = (float*)(ws + 256 + 33554432);
    float* bof   = (float*)(ws + 256 + 33566720);
    u16*   qkv   = (u16*)(ws + 256 + 33570816);
    u16*   y     = (u16*)(ws + 256 + 109068288);
    float2* tab  = (float2*)(ws + 256 + 134234112);

    detect_kernel<<<1, 256, 0, stream>>>((const u32*)d_in[0], flag);
    cvt_bf16_kernel<<<2048, 256, 0, stream>>>(d_in[0], xb,  12582912 / 8, flag);
    cvt_bf16_kernel<<<1536, 256, 0, stream>>>(d_in[1], Wqb, 3145728 / 8, flag);
    cvt_bf16_kernel<<<512,  256, 0, stream>>>(d_in[3], Wob, 1048576 / 8, flag);
    cvt_f32_kernel<<<12, 256, 0, stream>>>(d_in[2], bqf, 3072, flag);
    cvt_f32_kernel<<<4,  256, 0, stream>>>(d_in[4], bof, 1024, flag);
    rope_table_kernel<<<768 * 512 / 256, 256, 0, stream>>>(tab);

    // QKV GEMM with fused bias + RoPE epilogue
    gemm_bias_kernel<<<dim3(96, 24), 256, 0, stream>>>(xb, Wqb, bqf, qkv, 12288, 3072, 1024, flag, 0, tab, 1);
    attn_kernel<<<dim3(12, 16, 16), 256, 0, stream>>>(qkv, y);
    gemm_bias_kernel<<<dim3(96, 8), 256, 0, stream>>>(y, Wob, bof, d_out, 12288, 1024, 1024, flag, 1, tab, 0);
}